// Round 12
// baseline (1647.333 us; speedup 1.0000x reference)
//
#include <hip/hip_runtime.h>
#include <hip/hip_cooperative_groups.h>
namespace cg = cooperative_groups;

#define N_NODES   10000
#define IN_DIM    512
#define HID_DIM   512
#define OUT_DIM   256
#define N_CLASSES 8
#define N_GRAPHS  64
#define NB        1536   // cooperative grid blocks (6 per CU)

typedef __attribute__((ext_vector_type(8))) __bf16 bf16x8;
typedef __attribute__((ext_vector_type(4))) float f32x4;
typedef __attribute__((ext_vector_type(8))) unsigned short ushort8;
typedef __attribute__((ext_vector_type(4))) unsigned short ushort4v;
typedef unsigned short us;

__device__ __forceinline__ us f2bf(float f) {
    union { float f; unsigned int u; } v; v.f = f;
    unsigned int r = v.u + 0x7FFFu + ((v.u >> 16) & 1u);   // RTNE
    return (us)(r >> 16);
}
__device__ __forceinline__ float bf2f(us u) {
    union { unsigned int u; float f; } v; v.u = ((unsigned int)u) << 16;
    return v.f;
}
__device__ __forceinline__ void gload16(const us* g, us* l) {
    __builtin_amdgcn_global_load_lds(
        (const __attribute__((address_space(1))) unsigned int*)g,
        (__attribute__((address_space(3))) unsigned int*)l, 16, 0, 0);
}

// ================= shared device bodies =================

// one 32x32 W-transpose tile job (job 0..255 -> W1, 256..383 -> W2)
__device__ __forceinline__ void transpose_job(int job, int t, const float* W1, us* W1t,
                                              const float* W2, us* W2t, char* smem) {
    float (*tt)[33] = (float(*)[33])smem;
    const float* W; us* Wt; int K, N, bn, bk;
    if (job < 256) { W = W1; Wt = W1t; K = IN_DIM;  N = HID_DIM; bn = (job & 15) * 32; bk = (job >> 4) * 32; }
    else { int j2 = job - 256; W = W2; Wt = W2t; K = HID_DIM; N = OUT_DIM; bn = (j2 & 7) * 32; bk = (j2 >> 3) * 32; }
    int tx = t & 31, ty = t >> 5;
    #pragma unroll
    for (int j = 0; j < 32; j += 8)
        tt[ty + j][tx] = W[(size_t)(bk + ty + j) * N + bn + tx];
    __syncthreads();
    #pragma unroll
    for (int j = 0; j < 32; j += 8)
        Wt[(size_t)(bn + ty + j) * K + bk + tx] = f2bf(tt[tx][ty + j]);
}

__device__ __forceinline__ void cvt8_job(int j, const float* x, us* xb) {
    float4 f0 = *reinterpret_cast<const float4*>(&x[(size_t)j * 8]);
    float4 f1 = *reinterpret_cast<const float4*>(&x[(size_t)j * 8 + 4]);
    ushort8 v;
    v[0] = f2bf(f0.x); v[1] = f2bf(f0.y); v[2] = f2bf(f0.z); v[3] = f2bf(f0.w);
    v[4] = f2bf(f1.x); v[5] = f2bf(f1.y); v[6] = f2bf(f1.z); v[7] = f2bf(f1.w);
    *reinterpret_cast<ushort8*>(&xb[(size_t)j * 8]) = v;
}

// 128x64 MFMA tile (m97-style gload_lds staging), BK=32, 4 waves 2x2, frags 4x2
__device__ __forceinline__ void gemm_tile(const us* __restrict__ A, const us* __restrict__ Bt,
                                          us* __restrict__ C, int M, int N, int K,
                                          int rt, int ct, char* smem, int tid) {
    constexpr int BM = 128, BN = 64, BK = 32;
    constexpr int FM = 4, FN = 2;
    us* As = (us*)smem;            // 8 KB
    us* Bs = As + BM * BK;         // 4 KB
    int lane = tid & 63, wid = tid >> 6;
    int wm = wid >> 1, wn = wid & 1;
    int row0 = rt * BM, col0 = ct * BN;
    f32x4 acc[FM][FN] = {};
    for (int k0 = 0; k0 < K; k0 += BK) {
        #pragma unroll
        for (int i = 0; i < 2; i++) {                    // A: 512 16B-slots
            int sb = (wid * 2 + i) * 64;
            int s  = sb + lane;
            gload16(&A[(size_t)(row0 + (s >> 2)) * K + k0 + ((s & 3) << 3)], &As[sb * 8]);
        }
        {   int sb = wid * 64; int s = sb + lane;        // B: 256 slots
            gload16(&Bt[(size_t)(col0 + (s >> 2)) * K + k0 + ((s & 3) << 3)], &Bs[sb * 8]); }
        __syncthreads();
        int kk = (lane >> 4) << 3;
        int ra = (wm * 64 + (lane & 15)) * BK + kk;
        int rb = (wn * 32 + (lane & 15)) * BK + kk;
        bf16x8 a[FM], b[FN];
        #pragma unroll
        for (int m = 0; m < FM; m++) a[m] = *reinterpret_cast<const bf16x8*>(&As[ra + m * 16 * BK]);
        #pragma unroll
        for (int nn = 0; nn < FN; nn++) b[nn] = *reinterpret_cast<const bf16x8*>(&Bs[rb + nn * 16 * BK]);
        #pragma unroll
        for (int m = 0; m < FM; m++)
            #pragma unroll
            for (int nn = 0; nn < FN; nn++)
                acc[m][nn] = __builtin_amdgcn_mfma_f32_16x16x32_bf16(a[m], b[nn], acc[m][nn], 0, 0, 0);
        __syncthreads();
    }
    int rbase = row0 + wm * 64 + ((lane >> 4) << 2);
    int cbase = col0 + wn * 32 + (lane & 15);
    #pragma unroll
    for (int m = 0; m < FM; m++)
        #pragma unroll
        for (int nn = 0; nn < FN; nn++)
            #pragma unroll
            for (int j = 0; j < 4; j++) {
                int row = rbase + m * 16 + j;
                if (row < M) C[(size_t)row * N + cbase + nn * 16] = f2bf(acc[m][nn][j]);
            }
}

__device__ __forceinline__ void agg512_body(int i, int lane, const us* __restrict__ h,
                                            const int* __restrict__ offs, const int* __restrict__ csrs,
                                            const float* __restrict__ csrn, const float* __restrict__ dinv,
                                            const float* __restrict__ bias, us* __restrict__ outp) {
    int f = lane * 8;
    float di = dinv[i], w0 = di * di;
    ushort8 hv = *reinterpret_cast<const ushort8*>(&h[(size_t)i * 512 + f]);
    float acc[8];
    #pragma unroll
    for (int j = 0; j < 8; j++) acc[j] = bf2f(hv[j]) * w0;
    int p = offs[i], p1 = offs[i + 1];
    for (; p + 4 <= p1; p += 4) {
        int s0 = csrs[p], s1 = csrs[p + 1], s2 = csrs[p + 2], s3 = csrs[p + 3];
        float wa = csrn[p], wb = csrn[p + 1], wc = csrn[p + 2], wd = csrn[p + 3];
        ushort8 v0 = *reinterpret_cast<const ushort8*>(&h[(size_t)s0 * 512 + f]);
        ushort8 v1 = *reinterpret_cast<const ushort8*>(&h[(size_t)s1 * 512 + f]);
        ushort8 v2 = *reinterpret_cast<const ushort8*>(&h[(size_t)s2 * 512 + f]);
        ushort8 v3 = *reinterpret_cast<const ushort8*>(&h[(size_t)s3 * 512 + f]);
        #pragma unroll
        for (int j = 0; j < 8; j++) {
            acc[j] = fmaf(wa, bf2f(v0[j]), acc[j]);
            acc[j] = fmaf(wb, bf2f(v1[j]), acc[j]);
            acc[j] = fmaf(wc, bf2f(v2[j]), acc[j]);
            acc[j] = fmaf(wd, bf2f(v3[j]), acc[j]);
        }
    }
    for (; p < p1; p++) {
        int s = csrs[p]; float w = csrn[p];
        ushort8 v = *reinterpret_cast<const ushort8*>(&h[(size_t)s * 512 + f]);
        #pragma unroll
        for (int j = 0; j < 8; j++) acc[j] = fmaf(w, bf2f(v[j]), acc[j]);
    }
    float4 b0 = *reinterpret_cast<const float4*>(&bias[f]);
    float4 b1 = *reinterpret_cast<const float4*>(&bias[f + 4]);
    ushort8 r;
    r[0] = f2bf(fmaxf(acc[0] + b0.x, 0.f)); r[1] = f2bf(fmaxf(acc[1] + b0.y, 0.f));
    r[2] = f2bf(fmaxf(acc[2] + b0.z, 0.f)); r[3] = f2bf(fmaxf(acc[3] + b0.w, 0.f));
    r[4] = f2bf(fmaxf(acc[4] + b1.x, 0.f)); r[5] = f2bf(fmaxf(acc[5] + b1.y, 0.f));
    r[6] = f2bf(fmaxf(acc[6] + b1.z, 0.f)); r[7] = f2bf(fmaxf(acc[7] + b1.w, 0.f));
    *reinterpret_cast<ushort8*>(&outp[(size_t)i * 512 + f]) = r;
}

__device__ __forceinline__ void agg256_body(int i, int lane, const us* __restrict__ h,
                                            const int* __restrict__ offs, const int* __restrict__ csrs,
                                            const float* __restrict__ csrn, const float* __restrict__ dinv,
                                            const float* __restrict__ bias, us* __restrict__ outp) {
    int f = lane * 4;
    float di = dinv[i], w0 = di * di;
    ushort4v hv = *reinterpret_cast<const ushort4v*>(&h[(size_t)i * 256 + f]);
    float acc[4];
    #pragma unroll
    for (int j = 0; j < 4; j++) acc[j] = bf2f(hv[j]) * w0;
    int p = offs[i], p1 = offs[i + 1];
    for (; p + 4 <= p1; p += 4) {
        int s0 = csrs[p], s1 = csrs[p + 1], s2 = csrs[p + 2], s3 = csrs[p + 3];
        float wa = csrn[p], wb = csrn[p + 1], wc = csrn[p + 2], wd = csrn[p + 3];
        ushort4v v0 = *reinterpret_cast<const ushort4v*>(&h[(size_t)s0 * 256 + f]);
        ushort4v v1 = *reinterpret_cast<const ushort4v*>(&h[(size_t)s1 * 256 + f]);
        ushort4v v2 = *reinterpret_cast<const ushort4v*>(&h[(size_t)s2 * 256 + f]);
        ushort4v v3 = *reinterpret_cast<const ushort4v*>(&h[(size_t)s3 * 256 + f]);
        #pragma unroll
        for (int j = 0; j < 4; j++) {
            acc[j] = fmaf(wa, bf2f(v0[j]), acc[j]);
            acc[j] = fmaf(wb, bf2f(v1[j]), acc[j]);
            acc[j] = fmaf(wc, bf2f(v2[j]), acc[j]);
            acc[j] = fmaf(wd, bf2f(v3[j]), acc[j]);
        }
    }
    for (; p < p1; p++) {
        int s = csrs[p]; float w = csrn[p];
        ushort4v v = *reinterpret_cast<const ushort4v*>(&h[(size_t)s * 256 + f]);
        #pragma unroll
        for (int j = 0; j < 4; j++) acc[j] = fmaf(w, bf2f(v[j]), acc[j]);
    }
    float4 bv = *reinterpret_cast<const float4*>(&bias[f]);
    ushort4v r;
    r[0] = f2bf(fmaxf(acc[0] + bv.x, 0.f)); r[1] = f2bf(fmaxf(acc[1] + bv.y, 0.f));
    r[2] = f2bf(fmaxf(acc[2] + bv.z, 0.f)); r[3] = f2bf(fmaxf(acc[3] + bv.w, 0.f));
    *reinterpret_cast<ushort4v*>(&outp[(size_t)i * 256 + f]) = r;
}

__device__ __forceinline__ void pool_body(int g, int t, const us* __restrict__ agg2b,
                                          const int* __restrict__ start, const float* __restrict__ Wl,
                                          const float* __restrict__ bl, float* __restrict__ out,
                                          char* smem_raw) {
    float (*smem)[OUT_DIM] = (float(*)[OUT_DIM])smem_raw;   // 8 KB
    int ry = t >> 5;
    int cg = (t & 31) << 3;
    int s0 = start[g], s1 = start[g + 1];
    float acc[8] = {};
    for (int r = s0 + ry; r < s1; r += 8) {
        ushort8 v = *reinterpret_cast<const ushort8*>(&agg2b[(size_t)r * OUT_DIM + cg]);
        #pragma unroll
        for (int j = 0; j < 8; j++) acc[j] += bf2f(v[j]);
    }
    #pragma unroll
    for (int j = 0; j < 8; j++) smem[ry][cg + j] = acc[j];
    __syncthreads();
    float inv = 1.0f / fmaxf((float)(s1 - s0), 1.0f);
    float s = 0.f;
    #pragma unroll
    for (int r2 = 0; r2 < 8; r2++) s += smem[r2][t];
    float pooled_t = s * inv;
    __syncthreads();
    smem[0][t] = pooled_t;
    __syncthreads();
    int c = t >> 5, j = t & 31;
    float part = 0.f;
    #pragma unroll
    for (int m = 0; m < 8; m++) {
        int k = j + m * 32;
        part = fmaf(smem[0][k], Wl[k * N_CLASSES + c], part);
    }
    #pragma unroll
    for (int m = 16; m >= 1; m >>= 1) part += __shfl_xor(part, m, 32);
    if (j == 0) out[g * N_CLASSES + c] = part + bl[c];
}

// ================= cooperative mega-kernel =================
__global__ void __launch_bounds__(256, 6) mega_kernel(
    const float* x, const float* W1, const float* b1, const float* W2, const float* b2,
    const float* Wl, const float* bl, const int* src, const int* dst, const int* bat,
    float* out,
    us* xb, us* h1b, us* agg1b, us* h2b, us* agg2b, us* W1t, us* W2t,
    int* cnt, int* offs, int* pos, int* csrs, float* csrn, float* dinv, int* start, int* gpart,
    int n, int E) {
    cg::grid_group grid = cg::this_grid();
    __shared__ __align__(16) char smem[12 * 1024];
    int B = blockIdx.x, t = threadIdx.x;

    // ---- P0: cvt-x (B<1024) | W transpose (1024..1407) | degree count (1408..1535) ----
    // (cnt zeroed by host-side memsetAsync before this kernel)
    if (B < 1024) {
        const int total8 = N_NODES * IN_DIM / 8;
        for (int j = B * 256 + t; j < total8; j += 1024 * 256) cvt8_job(j, x, xb);
    } else if (B < 1408) {
        transpose_job(B - 1024, t, W1, W1t, W2, W2t, smem);
    } else {
        for (int e = (B - 1408) * 256 + t; e < E; e += 128 * 256) atomicAdd(&cnt[dst[e]], 1);
    }
    grid.sync();

    // ---- P1: per-block partial degree sums (7 nodes per block) ----
    if (t == 0) {
        int b0 = B * 7, s = 0;
        #pragma unroll
        for (int i = 0; i < 7; i++) { int idx = b0 + i; if (idx < n) s += cnt[idx]; }
        gpart[B] = s;
    }
    grid.sync();

    // ---- P2: block0 scans gpart (1536 -> exclusive) | blocks 1..632 run GEMM1 ----
    if (B == 0) {
        int* sp = (int*)smem;
        int v[6]; int s = 0;
        #pragma unroll
        for (int i = 0; i < 6; i++) { v[i] = gpart[t * 6 + i]; s += v[i]; }
        sp[t] = s;
        __syncthreads();
        for (int off = 1; off < 256; off <<= 1) {
            int u = (t >= off) ? sp[t - off] : 0;
            __syncthreads();
            sp[t] += u;
            __syncthreads();
        }
        int run = (t > 0) ? sp[t - 1] : 0;
        #pragma unroll
        for (int i = 0; i < 6; i++) { int old = v[i]; gpart[t * 6 + i] = run; run += old; }
    } else if (B <= 632) {
        int tile = B - 1;                               // 79 x 8 tiles of 128x64
        gemm_tile(xb, W1t, h1b, n, HID_DIM, IN_DIM, tile % 79, tile / 79, smem, t);
    }
    grid.sync();

    // ---- P3: scan write-back: offs/pos/dinv/start ----
    if (t == 0) {
        int b0 = B * 7;
        int run = gpart[B];
        for (int i = 0; i < 7; i++) {
            int idx = b0 + i;
            if (idx >= n) break;
            int c = cnt[idx];
            offs[idx] = run; pos[idx] = run;
            dinv[idx] = rsqrtf((float)(c + 1));          // self-loop => deg >= 1
            int bb = bat[idx];
            int bn2 = (idx + 1 < n) ? bat[idx + 1] : N_GRAPHS;
            for (int g = bb + 1; g <= bn2; g++) start[g] = idx + 1;
            if (idx == 0) for (int g = 0; g <= bb; g++) start[g] = 0;
            run += c;
            if (idx == n - 1) offs[n] = run;
        }
    }
    grid.sync();

    // ---- P4: fill CSR ----
    for (int e = B * 256 + t; e < E; e += NB * 256) {
        int s = src[e], d = dst[e];
        int p = atomicAdd(&pos[d], 1);
        csrs[p] = s;
        csrn[p] = dinv[s] * dinv[d];
    }
    grid.sync();

    // ---- P5: agg512 (wave per node, grid-stride) ----
    {
        int wid = B * 4 + (t >> 6), lane = t & 63;
        for (int i = wid; i < n; i += NB * 4) agg512_body(i, lane, h1b, offs, csrs, csrn, dinv, b1, agg1b);
    }
    grid.sync();

    // ---- P6: GEMM2 (79 x 4 tiles) ----
    if (B < 316) gemm_tile(agg1b, W2t, h2b, n, OUT_DIM, HID_DIM, B % 79, B / 79, smem, t);
    grid.sync();

    // ---- P7: agg256 ----
    {
        int wid = B * 4 + (t >> 6), lane = t & 63;
        for (int i = wid; i < n; i += NB * 4) agg256_body(i, lane, h2b, offs, csrs, csrn, dinv, b2, agg2b);
    }
    grid.sync();

    // ---- P8: pool + head ----
    if (B < N_GRAPHS) pool_body(B, t, agg2b, start, Wl, bl, out, smem);
}

// ================= fallback (non-cooperative) kernels =================
__global__ void count_deg_kernel(const int* __restrict__ dst, int* __restrict__ cnt, int E) {
    int e = blockIdx.x * blockDim.x + threadIdx.x;
    if (e < E) atomicAdd(&cnt[dst[e]], 1);
}

__global__ __launch_bounds__(1024) void scan_prep_kernel(const int* __restrict__ cnt,
                                                         int* __restrict__ offs, int* __restrict__ pos,
                                                         float* __restrict__ dinv,
                                                         const int* __restrict__ batch,
                                                         int* __restrict__ start, int n) {
    __shared__ int partial[1024];
    int tid = threadIdx.x;
    const int CH = (n + 1023) >> 10;
    int base = tid * CH;
    int s = 0;
    for (int i = 0; i < CH; i++) { int idx = base + i; if (idx < n) s += cnt[idx]; }
    partial[tid] = s;
    __syncthreads();
    for (int off = 1; off < 1024; off <<= 1) {
        int v = (tid >= off) ? partial[tid - off] : 0;
        __syncthreads();
        partial[tid] += v;
        __syncthreads();
    }
    int run = (tid > 0) ? partial[tid - 1] : 0;
    for (int i = 0; i < CH; i++) {
        int idx = base + i;
        if (idx < n) {
            int c = cnt[idx];
            offs[idx] = run; pos[idx] = run;
            dinv[idx] = rsqrtf((float)(c + 1));
            int b = batch[idx];
            int bn = (idx + 1 < n) ? batch[idx + 1] : N_GRAPHS;
            for (int g = b + 1; g <= bn; g++) start[g] = idx + 1;
            if (idx == 0) for (int g = 0; g <= b; g++) start[g] = 0;
            run += c;
        }
    }
    if (tid == 0) offs[n] = partial[1023];
}

__global__ void fill_csr_kernel(const int* __restrict__ src, const int* __restrict__ dst,
                                const float* __restrict__ dinv, int* __restrict__ pos,
                                int* __restrict__ csrs, float* __restrict__ csrn, int E) {
    int e = blockIdx.x * blockDim.x + threadIdx.x;
    if (e < E) {
        int s = src[e], d = dst[e];
        int p = atomicAdd(&pos[d], 1);
        csrs[p] = s;
        csrn[p] = dinv[s] * dinv[d];
    }
}

__global__ __launch_bounds__(256) void cvt_all_kernel(const float* __restrict__ W1, us* __restrict__ W1t,
                                                      const float* __restrict__ W2, us* __restrict__ W2t,
                                                      const float* __restrict__ x, us* __restrict__ xb,
                                                      int total8) {
    __shared__ __align__(16) char smem[12 * 1024];
    int b = blockIdx.x;
    if (b < 384) transpose_job(b, threadIdx.x, W1, W1t, W2, W2t, smem);
    else { int i = (b - 384) * 256 + threadIdx.x; if (i < total8) cvt8_job(i, x, xb); }
}

__global__ __launch_bounds__(256) void gemm_kernel_sa(const us* __restrict__ A, const us* __restrict__ Bt,
                                                      us* __restrict__ C, int M, int N, int K) {
    __shared__ __align__(16) char smem[12 * 1024];
    gemm_tile(A, Bt, C, M, N, K, blockIdx.x, blockIdx.y, smem, threadIdx.x);
}

__global__ __launch_bounds__(256) void agg512_kernel(const us* __restrict__ h, const int* __restrict__ offs,
                                                     const int* __restrict__ csrs, const float* __restrict__ csrn,
                                                     const float* __restrict__ dinv, const float* __restrict__ bias,
                                                     us* __restrict__ outp, int n) {
    int i = blockIdx.x * 4 + (threadIdx.x >> 6);
    if (i < n) agg512_body(i, threadIdx.x & 63, h, offs, csrs, csrn, dinv, bias, outp);
}

__global__ __launch_bounds__(256) void agg256_kernel(const us* __restrict__ h, const int* __restrict__ offs,
                                                     const int* __restrict__ csrs, const float* __restrict__ csrn,
                                                     const float* __restrict__ dinv, const float* __restrict__ bias,
                                                     us* __restrict__ outp, int n) {
    int i = blockIdx.x * 4 + (threadIdx.x >> 6);
    if (i < n) agg256_body(i, threadIdx.x & 63, h, offs, csrs, csrn, dinv, bias, outp);
}

__global__ __launch_bounds__(256) void pool_head_kernel(const us* __restrict__ agg2b,
                                                        const int* __restrict__ start,
                                                        const float* __restrict__ Wl,
                                                        const float* __restrict__ bl,
                                                        float* __restrict__ out) {
    __shared__ __align__(16) char smem[12 * 1024];
    pool_body(blockIdx.x, threadIdx.x, agg2b, start, Wl, bl, out, smem);
}

// ================= launch =================
extern "C" void kernel_launch(void* const* d_in, const int* in_sizes, int n_in,
                              void* d_out, int out_size, void* d_ws, size_t ws_size,
                              hipStream_t stream) {
    const float* x   = (const float*)d_in[0];
    const float* W1  = (const float*)d_in[1];
    const float* b1  = (const float*)d_in[2];
    const float* W2  = (const float*)d_in[3];
    const float* b2  = (const float*)d_in[4];
    const float* Wl  = (const float*)d_in[5];
    const float* bl  = (const float*)d_in[6];
    const int*   ei  = (const int*)d_in[7];
    const int*   bat = (const int*)d_in[8];
    float* out = (float*)d_out;

    int n = N_NODES;
    int E = in_sizes[7] / 2;
    const int* src = ei;
    const int* dst = ei + E;

    // workspace layout, 16B-aligned chunks
    us* xb    = (us*)d_ws;                          // n*512 bf16
    us* h2b   = xb + (size_t)n * IN_DIM;            // n*256 bf16
    us* agg2b = h2b + (size_t)n * OUT_DIM;          // n*256 bf16
    us* h1b   = agg2b + (size_t)n * OUT_DIM;        // n*512 bf16
    us* agg1b = h1b + (size_t)n * HID_DIM;          // n*512 bf16
    us* W1t   = agg1b + (size_t)n * HID_DIM;        // 512*512 bf16
    us* W2t   = W1t + IN_DIM * HID_DIM;             // 256*512 bf16
    int*   cnt   = (int*)(W2t + HID_DIM * OUT_DIM);
    int*   offs  = cnt + n;                         // n+1
    int*   pos   = offs + n + 1;                    // n
    int*   csrs  = pos + n;                         // E
    float* csrn  = (float*)(csrs + E);              // E
    float* dinv  = csrn + E;                        // n
    int*   start = (int*)(dinv + n);                // N_GRAPHS+1
    int*   gpart = start + N_GRAPHS + 1;            // NB

    hipMemsetAsync(cnt, 0, n * sizeof(int), stream);

    void* kargs[] = {
        (void*)&x, (void*)&W1, (void*)&b1, (void*)&W2, (void*)&b2,
        (void*)&Wl, (void*)&bl, (void*)&src, (void*)&dst, (void*)&bat,
        (void*)&out,
        (void*)&xb, (void*)&h1b, (void*)&agg1b, (void*)&h2b, (void*)&agg2b,
        (void*)&W1t, (void*)&W2t,
        (void*)&cnt, (void*)&offs, (void*)&pos, (void*)&csrs, (void*)&csrn,
        (void*)&dinv, (void*)&start, (void*)&gpart,
        (void*)&n, (void*)&E
    };
    hipError_t err = hipLaunchCooperativeKernel((void*)mega_kernel, dim3(NB), dim3(256),
                                                kargs, 0, stream);
    if (err != hipSuccess) {
        // fallback: measured 10-kernel path (identical math)
        count_deg_kernel<<<(E + 255) / 256, 256, 0, stream>>>(dst, cnt, E);
        scan_prep_kernel<<<1, 1024, 0, stream>>>(cnt, offs, pos, dinv, bat, start, n);
        fill_csr_kernel<<<(E + 255) / 256, 256, 0, stream>>>(src, dst, dinv, pos, csrs, csrn, E);
        int total8 = n * IN_DIM / 8;
        cvt_all_kernel<<<384 + (total8 + 255) / 256, 256, 0, stream>>>(W1, W1t, W2, W2t, x, xb, total8);
        gemm_kernel_sa<<<dim3(79, HID_DIM / 64), 256, 0, stream>>>(xb, W1t, h1b, n, HID_DIM, IN_DIM);
        agg512_kernel<<<(n + 3) / 4, 256, 0, stream>>>(h1b, offs, csrs, csrn, dinv, b1, agg1b, n);
        gemm_kernel_sa<<<dim3(79, OUT_DIM / 64), 256, 0, stream>>>(agg1b, W2t, h2b, n, OUT_DIM, HID_DIM);
        agg256_kernel<<<(n + 3) / 4, 256, 0, stream>>>(h2b, offs, csrs, csrn, dinv, b2, agg2b, n);
        pool_head_kernel<<<N_GRAPHS, OUT_DIM, 0, stream>>>(agg2b, start, Wl, bl, out);
    }
}

// Round 14
// 207.466 us; speedup vs baseline: 7.9403x; 7.9403x over previous
//
#include <hip/hip_runtime.h>

#define N_NODES   10000
#define IN_DIM    512
#define HID_DIM   512
#define OUT_DIM   256
#define N_CLASSES 8
#define N_GRAPHS  64

typedef __attribute__((ext_vector_type(8))) __bf16 bf16x8;
typedef __attribute__((ext_vector_type(4))) float f32x4;
typedef __attribute__((ext_vector_type(8))) unsigned short ushort8;
typedef __attribute__((ext_vector_type(4))) unsigned short ushort4v;
typedef unsigned short us;

__device__ __forceinline__ us f2bf(float f) {
    union { float f; unsigned int u; } v; v.f = f;
    unsigned int r = v.u + 0x7FFFu + ((v.u >> 16) & 1u);   // RTNE
    return (us)(r >> 16);
}
__device__ __forceinline__ float bf2f(us u) {
    union { unsigned int u; float f; } v; v.u = ((unsigned int)u) << 16;
    return v.f;
}
__device__ __forceinline__ void gload16(const us* g, us* l) {
    __builtin_amdgcn_global_load_lds(
        (const __attribute__((address_space(1))) unsigned int*)g,
        (__attribute__((address_space(3))) unsigned int*)l, 16, 0, 0);
}

// ---------------- cvt + transpose + degree count, one launch ----------------
// blocks [0,384): W1/W2 32x32 transpose tiles
// blocks [384, 384+2500): x fp32->bf16 (ushort8 units)
// blocks [384+2500, ...): edge degree count (atomics on cnt)
__global__ __launch_bounds__(256) void cvt_all_kernel(const float* __restrict__ W1, us* __restrict__ W1t,
                                                      const float* __restrict__ W2, us* __restrict__ W2t,
                                                      const float* __restrict__ x, us* __restrict__ xb,
                                                      int total8,
                                                      const int* __restrict__ dst, int* __restrict__ cnt,
                                                      int E) {
    int b = blockIdx.x;
    if (b < 384) {
        __shared__ float t[32][33];
        const float* W; us* Wt; int K, N, bn, bk;
        if (b < 256) { W = W1; Wt = W1t; K = IN_DIM;  N = HID_DIM; bn = (b & 15) * 32; bk = (b >> 4) * 32; }
        else { int b2 = b - 256; W = W2; Wt = W2t; K = HID_DIM; N = OUT_DIM; bn = (b2 & 7) * 32; bk = (b2 >> 3) * 32; }
        int tx = threadIdx.x & 31, ty = threadIdx.x >> 5;   // 32 x 8
        #pragma unroll
        for (int j = 0; j < 32; j += 8)
            t[ty + j][tx] = W[(size_t)(bk + ty + j) * N + bn + tx];
        __syncthreads();
        #pragma unroll
        for (int j = 0; j < 32; j += 8)
            Wt[(size_t)(bn + ty + j) * K + bk + tx] = f2bf(t[tx][ty + j]);
    } else if (b < 384 + 2500) {
        int i = (b - 384) * 256 + threadIdx.x;
        if (i < total8) {
            float4 f0 = *reinterpret_cast<const float4*>(&x[(size_t)i * 8]);
            float4 f1 = *reinterpret_cast<const float4*>(&x[(size_t)i * 8 + 4]);
            ushort8 v;
            v[0] = f2bf(f0.x); v[1] = f2bf(f0.y); v[2] = f2bf(f0.z); v[3] = f2bf(f0.w);
            v[4] = f2bf(f1.x); v[5] = f2bf(f1.y); v[6] = f2bf(f1.z); v[7] = f2bf(f1.w);
            *reinterpret_cast<ushort8*>(&xb[(size_t)i * 8]) = v;
        }
    } else {
        int e = (b - 384 - 2500) * 256 + threadIdx.x;
        if (e < E) atomicAdd(&cnt[dst[e]], 1);
    }
}

// ---------------- exclusive scan + dinv + graph bounds (one block) ----------------
__global__ __launch_bounds__(1024) void scan_prep_kernel(const int* __restrict__ cnt,
                                                         int* __restrict__ offs,
                                                         int* __restrict__ pos,
                                                         float* __restrict__ dinv,
                                                         const int* __restrict__ batch,
                                                         int* __restrict__ start, int n) {
    __shared__ int partial[1024];
    int tid = threadIdx.x;
    const int CH = (n + 1023) >> 10;
    int base = tid * CH;
    int s = 0;
    for (int i = 0; i < CH; i++) { int idx = base + i; if (idx < n) s += cnt[idx]; }
    partial[tid] = s;
    __syncthreads();
    for (int off = 1; off < 1024; off <<= 1) {
        int v = (tid >= off) ? partial[tid - off] : 0;
        __syncthreads();
        partial[tid] += v;
        __syncthreads();
    }
    int run = (tid > 0) ? partial[tid - 1] : 0;
    for (int i = 0; i < CH; i++) {
        int idx = base + i;
        if (idx < n) {
            int c = cnt[idx];
            offs[idx] = run; pos[idx] = run;
            dinv[idx] = rsqrtf((float)(c + 1));     // self-loop => deg >= 1
            int b  = batch[idx];
            int bn = (idx + 1 < n) ? batch[idx + 1] : N_GRAPHS;
            for (int g = b + 1; g <= bn; g++) start[g] = idx + 1;
            if (idx == 0) for (int g = 0; g <= b; g++) start[g] = 0;
            run += c;
        }
    }
    if (tid == 0) offs[n] = partial[1023];
}

// ---------------- bucket edges into CSR (by dst) ----------------
__global__ void fill_csr_kernel(const int* __restrict__ src, const int* __restrict__ dst,
                                const float* __restrict__ dinv, int* __restrict__ pos,
                                int* __restrict__ csrs, float* __restrict__ csrn, int E) {
    int e = blockIdx.x * blockDim.x + threadIdx.x;
    if (e < E) {
        int s = src[e], d = dst[e];
        int p = atomicAdd(&pos[d], 1);
        csrs[p] = s;
        csrn[p] = dinv[s] * dinv[d];
    }
}

// ---------------- bf16 MFMA GEMM (m97 structure): C[M,N] = A[M,K] @ Bt[N,K]^T ----------------
// Linear LDS, global_load_lds width-16 staging, BK=32, 4 waves (2x2).
// A-tile rows past M read garbage (adjacent ws regions) — those C rows are never stored.
template<int BM, int BN>
__global__ __launch_bounds__(256) void mfma_gemm_kernel(const us* __restrict__ A,
                                                        const us* __restrict__ Bt,
                                                        us* __restrict__ C,
                                                        int M, int N, int K) {
    constexpr int BK = 32;
    constexpr int FM = BM / 32, FN = BN / 32;
    __shared__ us As[BM * BK];
    __shared__ us Bs[BN * BK];
    int tid  = threadIdx.x;
    int lane = tid & 63;
    int wid  = tid >> 6;
    int wm = wid >> 1, wn = wid & 1;
    int row0 = blockIdx.x * BM, col0 = blockIdx.y * BN;

    f32x4 acc[FM][FN] = {};

    for (int k0 = 0; k0 < K; k0 += BK) {
        #pragma unroll
        for (int i = 0; i < BM / 64; i++) {
            int sb = (wid * (BM / 64) + i) * 64;          // wave-uniform slot base
            int s  = sb + lane;
            gload16(&A[(size_t)(row0 + (s >> 2)) * K + k0 + ((s & 3) << 3)], &As[sb * 8]);
        }
        #pragma unroll
        for (int i = 0; i < BN / 64; i++) {
            int sb = (wid * (BN / 64) + i) * 64;
            int s  = sb + lane;
            gload16(&Bt[(size_t)(col0 + (s >> 2)) * K + k0 + ((s & 3) << 3)], &Bs[sb * 8]);
        }
        __syncthreads();   // compiler drains vmcnt before s_barrier

        int kk = (lane >> 4) << 3;
        int ra = (wm * (BM / 2) + (lane & 15)) * BK + kk;
        int rb = (wn * (BN / 2) + (lane & 15)) * BK + kk;
        bf16x8 a[FM], b[FN];
        #pragma unroll
        for (int m = 0; m < FM; m++)
            a[m] = *reinterpret_cast<const bf16x8*>(&As[ra + m * 16 * BK]);
        #pragma unroll
        for (int nn = 0; nn < FN; nn++)
            b[nn] = *reinterpret_cast<const bf16x8*>(&Bs[rb + nn * 16 * BK]);
        #pragma unroll
        for (int m = 0; m < FM; m++)
            #pragma unroll
            for (int nn = 0; nn < FN; nn++)
                acc[m][nn] = __builtin_amdgcn_mfma_f32_16x16x32_bf16(a[m], b[nn], acc[m][nn], 0, 0, 0);
        __syncthreads();
    }

    // C/D layout (HW-verified): col = lane&15, row = (lane>>4)*4 + reg
    int rbase = row0 + wm * (BM / 2) + ((lane >> 4) << 2);
    int cbase = col0 + wn * (BN / 2) + (lane & 15);
    #pragma unroll
    for (int m = 0; m < FM; m++) {
        #pragma unroll
        for (int nn = 0; nn < FN; nn++) {
            #pragma unroll
            for (int j = 0; j < 4; j++) {
                int row = rbase + m * 16 + j;
                if (row < M) C[(size_t)row * N + cbase + nn * 16] = f2bf(acc[m][nn][j]);
            }
        }
    }
}

// ---------------- layer-1 aggregation: wave/node, F=512, 4-deep gather pipeline ----------------
__global__ __launch_bounds__(256) void agg512_kernel(const us* __restrict__ h,
                                                     const int* __restrict__ offs,
                                                     const int* __restrict__ csrs,
                                                     const float* __restrict__ csrn,
                                                     const float* __restrict__ dinv,
                                                     const float* __restrict__ bias,
                                                     us* __restrict__ outp, int n) {
    int wid = threadIdx.x >> 6, lane = threadIdx.x & 63;
    int i = blockIdx.x * 4 + wid;
    if (i >= n) return;
    int f = lane * 8;
    float di = dinv[i], w0 = di * di;
    ushort8 hv = *reinterpret_cast<const ushort8*>(&h[(size_t)i * 512 + f]);
    float acc[8];
    #pragma unroll
    for (int j = 0; j < 8; j++) acc[j] = bf2f(hv[j]) * w0;
    int p = offs[i], p1 = offs[i + 1];
    for (; p + 4 <= p1; p += 4) {
        int s0 = csrs[p], s1 = csrs[p + 1], s2 = csrs[p + 2], s3 = csrs[p + 3];
        float wa = csrn[p], wb = csrn[p + 1], wc = csrn[p + 2], wd = csrn[p + 3];
        ushort8 v0 = *reinterpret_cast<const ushort8*>(&h[(size_t)s0 * 512 + f]);
        ushort8 v1 = *reinterpret_cast<const ushort8*>(&h[(size_t)s1 * 512 + f]);
        ushort8 v2 = *reinterpret_cast<const ushort8*>(&h[(size_t)s2 * 512 + f]);
        ushort8 v3 = *reinterpret_cast<const ushort8*>(&h[(size_t)s3 * 512 + f]);
        #pragma unroll
        for (int j = 0; j < 8; j++) {
            acc[j] = fmaf(wa, bf2f(v0[j]), acc[j]);
            acc[j] = fmaf(wb, bf2f(v1[j]), acc[j]);
            acc[j] = fmaf(wc, bf2f(v2[j]), acc[j]);
            acc[j] = fmaf(wd, bf2f(v3[j]), acc[j]);
        }
    }
    for (; p < p1; p++) {
        int s = csrs[p]; float w = csrn[p];
        ushort8 v = *reinterpret_cast<const ushort8*>(&h[(size_t)s * 512 + f]);
        #pragma unroll
        for (int j = 0; j < 8; j++) acc[j] = fmaf(w, bf2f(v[j]), acc[j]);
    }
    float4 b0 = *reinterpret_cast<const float4*>(&bias[f]);
    float4 b1 = *reinterpret_cast<const float4*>(&bias[f + 4]);
    ushort8 r;
    r[0] = f2bf(fmaxf(acc[0] + b0.x, 0.f)); r[1] = f2bf(fmaxf(acc[1] + b0.y, 0.f));
    r[2] = f2bf(fmaxf(acc[2] + b0.z, 0.f)); r[3] = f2bf(fmaxf(acc[3] + b0.w, 0.f));
    r[4] = f2bf(fmaxf(acc[4] + b1.x, 0.f)); r[5] = f2bf(fmaxf(acc[5] + b1.y, 0.f));
    r[6] = f2bf(fmaxf(acc[6] + b1.z, 0.f)); r[7] = f2bf(fmaxf(acc[7] + b1.w, 0.f));
    *reinterpret_cast<ushort8*>(&outp[(size_t)i * 512 + f]) = r;
}

// ---------------- layer-2 aggregation: wave/node, F=256, 4-deep gather pipeline ----------------
__global__ __launch_bounds__(256) void agg256_kernel(const us* __restrict__ h,
                                                     const int* __restrict__ offs,
                                                     const int* __restrict__ csrs,
                                                     const float* __restrict__ csrn,
                                                     const float* __restrict__ dinv,
                                                     const float* __restrict__ bias,
                                                     us* __restrict__ outp, int n) {
    int wid = threadIdx.x >> 6, lane = threadIdx.x & 63;
    int i = blockIdx.x * 4 + wid;
    if (i >= n) return;
    int f = lane * 4;
    float di = dinv[i], w0 = di * di;
    ushort4v hv = *reinterpret_cast<const ushort4v*>(&h[(size_t)i * 256 + f]);
    float acc[4];
    #pragma unroll
    for (int j = 0; j < 4; j++) acc[j] = bf2f(hv[j]) * w0;
    int p = offs[i], p1 = offs[i + 1];
    for (; p + 4 <= p1; p += 4) {
        int s0 = csrs[p], s1 = csrs[p + 1], s2 = csrs[p + 2], s3 = csrs[p + 3];
        float wa = csrn[p], wb = csrn[p + 1], wc = csrn[p + 2], wd = csrn[p + 3];
        ushort4v v0 = *reinterpret_cast<const ushort4v*>(&h[(size_t)s0 * 256 + f]);
        ushort4v v1 = *reinterpret_cast<const ushort4v*>(&h[(size_t)s1 * 256 + f]);
        ushort4v v2 = *reinterpret_cast<const ushort4v*>(&h[(size_t)s2 * 256 + f]);
        ushort4v v3 = *reinterpret_cast<const ushort4v*>(&h[(size_t)s3 * 256 + f]);
        #pragma unroll
        for (int j = 0; j < 4; j++) {
            acc[j] = fmaf(wa, bf2f(v0[j]), acc[j]);
            acc[j] = fmaf(wb, bf2f(v1[j]), acc[j]);
            acc[j] = fmaf(wc, bf2f(v2[j]), acc[j]);
            acc[j] = fmaf(wd, bf2f(v3[j]), acc[j]);
        }
    }
    for (; p < p1; p++) {
        int s = csrs[p]; float w = csrn[p];
        ushort4v v = *reinterpret_cast<const ushort4v*>(&h[(size_t)s * 256 + f]);
        #pragma unroll
        for (int j = 0; j < 4; j++) acc[j] = fmaf(w, bf2f(v[j]), acc[j]);
    }
    float4 bv = *reinterpret_cast<const float4*>(&bias[f]);
    ushort4v r;
    r[0] = f2bf(fmaxf(acc[0] + bv.x, 0.f)); r[1] = f2bf(fmaxf(acc[1] + bv.y, 0.f));
    r[2] = f2bf(fmaxf(acc[2] + bv.z, 0.f)); r[3] = f2bf(fmaxf(acc[3] + bv.w, 0.f));
    *reinterpret_cast<ushort4v*>(&outp[(size_t)i * 256 + f]) = r;
}

// ---------------- pool (sorted batch, contiguous ranges) + classifier head ----------------
__global__ __launch_bounds__(256) void pool_head_kernel(const us* __restrict__ agg2b,
                                                        const int* __restrict__ start,
                                                        const float* __restrict__ Wl,
                                                        const float* __restrict__ bl,
                                                        float* __restrict__ out) {
    __shared__ float smem[8][OUT_DIM];   // 8 KB
    int g = blockIdx.x;
    int t = threadIdx.x;
    int ry = t >> 5;            // 0..7
    int cg = (t & 31) << 3;     // 0,8,...,248
    int s0 = start[g], s1 = start[g + 1];
    float acc[8] = {};
    for (int r = s0 + ry; r < s1; r += 8) {
        ushort8 v = *reinterpret_cast<const ushort8*>(&agg2b[(size_t)r * OUT_DIM + cg]);
        #pragma unroll
        for (int j = 0; j < 8; j++) acc[j] += bf2f(v[j]);
    }
    #pragma unroll
    for (int j = 0; j < 8; j++) smem[ry][cg + j] = acc[j];
    __syncthreads();
    float inv = 1.0f / fmaxf((float)(s1 - s0), 1.0f);
    float s = 0.f;
    #pragma unroll
    for (int r2 = 0; r2 < 8; r2++) s += smem[r2][t];
    float pooled_t = s * inv;
    __syncthreads();
    smem[0][t] = pooled_t;
    __syncthreads();
    int c = t >> 5, j = t & 31;
    float part = 0.f;
    #pragma unroll
    for (int m = 0; m < 8; m++) {
        int k = j + m * 32;
        part = fmaf(smem[0][k], Wl[k * N_CLASSES + c], part);
    }
    #pragma unroll
    for (int m = 16; m >= 1; m >>= 1) part += __shfl_xor(part, m, 32);
    if (j == 0) out[g * N_CLASSES + c] = part + bl[c];
}

extern "C" void kernel_launch(void* const* d_in, const int* in_sizes, int n_in,
                              void* d_out, int out_size, void* d_ws, size_t ws_size,
                              hipStream_t stream) {
    const float* x   = (const float*)d_in[0];
    const float* W1  = (const float*)d_in[1];
    const float* b1  = (const float*)d_in[2];
    const float* W2  = (const float*)d_in[3];
    const float* b2  = (const float*)d_in[4];
    const float* Wl  = (const float*)d_in[5];
    const float* bl  = (const float*)d_in[6];
    const int*   ei  = (const int*)d_in[7];
    const int*   bat = (const int*)d_in[8];
    float* out = (float*)d_out;

    const int n = N_NODES;
    const int E = in_sizes[7] / 2;
    const int* src = ei;
    const int* dst = ei + E;

    // workspace layout, 16B-aligned chunks
    us* xb    = (us*)d_ws;                          // n*512 bf16
    us* h2b   = xb + (size_t)n * IN_DIM;            // n*256 bf16
    us* agg2b = h2b + (size_t)n * OUT_DIM;          // n*256 bf16
    us* h1b   = agg2b + (size_t)n * OUT_DIM;        // n*512 bf16
    us* agg1b = h1b + (size_t)n * HID_DIM;          // n*512 bf16
    us* W1t   = agg1b + (size_t)n * HID_DIM;        // 512*512 bf16
    us* W2t   = W1t + IN_DIM * HID_DIM;             // 256*512 bf16
    int*   cnt   = (int*)(W2t + HID_DIM * OUT_DIM);
    int*   offs  = cnt + n;                         // n+1
    int*   pos   = offs + n + 1;                    // n
    int*   csrs  = pos + n;                         // E
    float* csrn  = (float*)(csrs + E);              // E
    float* dinv  = csrn + E;                        // n
    int*   start = (int*)(dinv + n);                // N_GRAPHS+1

    hipMemsetAsync(cnt, 0, n * sizeof(int), stream);

    // cvt + transposes + degree count in one launch
    int total8 = n * IN_DIM / 8;                    // 640000 -> 2500 blocks
    int nEdgeBlocks = (E + 255) / 256;
    cvt_all_kernel<<<384 + 2500 + nEdgeBlocks, 256, 0, stream>>>(
        W1, W1t, W2, W2t, x, xb, total8, dst, cnt, E);

    scan_prep_kernel<<<1, 1024, 0, stream>>>(cnt, offs, pos, dinv, bat, start, n);
    fill_csr_kernel<<<nEdgeBlocks, 256, 0, stream>>>(src, dst, dinv, pos, csrs, csrn, E);

    // layer 1: h1b = bf16(xb @ W1) ; agg1b = bf16(relu(A_norm @ h1 + b1))
    dim3 g1((n + 127) / 128, HID_DIM / 128);
    mfma_gemm_kernel<128, 128><<<g1, 256, 0, stream>>>(xb, W1t, h1b, n, HID_DIM, IN_DIM);
    agg512_kernel<<<(n + 3) / 4, 256, 0, stream>>>(h1b, offs, csrs, csrn, dinv, b1, agg1b, n);

    // layer 2: h2b = bf16(agg1b @ W2) ; agg2b = bf16(relu(A_norm @ h2 + b2))
    dim3 g2((n + 127) / 128, OUT_DIM / 64);
    mfma_gemm_kernel<128, 64><<<g2, 256, 0, stream>>>(agg1b, W2t, h2b, n, OUT_DIM, HID_DIM);
    agg256_kernel<<<(n + 3) / 4, 256, 0, stream>>>(h2b, offs, csrs, csrn, dinv, b2, agg2b, n);

    // pool over contiguous per-graph node ranges + head
    pool_head_kernel<<<N_GRAPHS, OUT_DIM, 0, stream>>>(agg2b, start, Wl, bl, out);
}